// Round 9
// baseline (959.856 us; speedup 1.0000x reference)
//
#include <hip/hip_runtime.h>
#include <math.h>

#define N_NODES 10000
#define N_EDGES 80000
#define N_GRAPH 64
#define DD 64
#define HIDW 128
#define F_IN 14
#define EAD 4

typedef _Float16 f16x8 __attribute__((ext_vector_type(8)));
typedef float f32x4 __attribute__((ext_vector_type(4)));

__device__ __forceinline__ float sigmoidf_(float x){ return 1.0f/(1.0f+expf(-x)); }

// ---------- prep kernels ----------

// Pack h2_w into fp16 MFMA B-fragment order with i-major K within each h-chunk:
// chunk c (8 chunks of CH=16 h), k_local = st*32 + kb*8 + j (st 0..31), i = k_local>>4,
// h = c*16 + (k_local&15), o = cg*16 + (lane&15).
// Bp[(((c*32+st)*4+cg)*64+lane)*8+j] = h2w[h*4096 + i*64 + o]
__global__ void k_prep_bpack(const float* __restrict__ h2w, _Float16* __restrict__ Bp){
  int idx = blockIdx.x*256 + threadIdx.x;   // < 2^19
  int j = idx & 7, l = (idx >> 3) & 63, cg = (idx >> 9) & 3, st = (idx >> 11) & 31, c = idx >> 16;
  int k = st*32 + ((l >> 4) << 3) + j;
  int i = k >> 4;
  int h = c*16 + (k & 15);
  int o = cg*16 + (l & 15);
  Bp[idx] = (_Float16)h2w[(size_t)h*4096 + i*64 + o];
}

// transpose GRU / LSTM weight matrices to k-major for coalesced reads
__global__ void k_prep_wT(const float* __restrict__ gih, const float* __restrict__ ghh,
                          const float* __restrict__ lih, const float* __restrict__ lhh,
                          float* __restrict__ WihT, float* __restrict__ WhhT,
                          float* __restrict__ IhT,  float* __restrict__ HhT){
  int idx = blockIdx.x*256 + threadIdx.x;
  if (idx < 12288){ int k=idx/192, j=idx%192; WihT[idx]=gih[j*64+k]; return; }
  idx -= 12288;
  if (idx < 12288){ int k=idx/192, j=idx%192; WhhT[idx]=ghh[j*64+k]; return; }
  idx -= 12288;
  if (idx < 32768){ int k=idx>>8, j=idx&255; IhT[idx]=lih[j*128+k]; return; }
  idx -= 32768;
  if (idx < 16384){ int k=idx>>8, j=idx&255; HhT[idx]=lhh[j*64+k]; return; }
}

// ---------- CSR build (sort edges by target) ----------

__global__ void k_count(const int* __restrict__ tgt, int* __restrict__ cnt){
  int e = blockIdx.x*256 + threadIdx.x;
  if (e < N_EDGES) atomicAdd(&cnt[tgt[e]], 1);
}

__global__ __launch_bounds__(1024) void k_scan(const int* __restrict__ cnt, int* __restrict__ offs,
                                               int* __restrict__ cursor, float* __restrict__ deg){
  __shared__ int sc[1024];
  int t = threadIdx.x;
  int base = t*10;
  int loc[10]; int tot = 0;
  #pragma unroll
  for (int j=0;j<10;++j){
    int i = base+j;
    int c = (i < N_NODES) ? cnt[i] : 0;
    loc[j] = tot; tot += c;
  }
  sc[t] = tot; __syncthreads();
  for (int st=1; st<1024; st<<=1){
    int v = (t>=st) ? sc[t-st] : 0;
    __syncthreads();
    sc[t] += v;
    __syncthreads();
  }
  int ex = sc[t] - tot;
  #pragma unroll
  for (int j=0;j<10;++j){
    int i = base+j;
    if (i < N_NODES){
      int o = ex + loc[j];
      offs[i] = o; cursor[i] = o;
      int c = cnt[i];
      deg[i] = (float)(c > 0 ? c : 1);
    }
  }
  if (t == 1023) offs[N_NODES] = sc[1023];
}

__global__ void k_sortE(const int* __restrict__ tgt, const int* __restrict__ src,
                        int* __restrict__ cursor, int* __restrict__ srcS, int* __restrict__ pos){
  int e = blockIdx.x*256 + threadIdx.x;
  if (e < N_EDGES){
    int p = atomicAdd(&cursor[tgt[e]], 1);
    srcS[p] = src[e];
    pos[e] = p;
  }
}

__global__ void k_graphoff(const int* __restrict__ batch, int* __restrict__ goff){
  int g = threadIdx.x;
  if (g > N_GRAPH) return;
  int lo = 0, hi = N_NODES;
  while (lo < hi){ int mid = (lo+hi)>>1; if (batch[mid] < g) lo = mid+1; else hi = mid; }
  goff[g] = lo;
}

// ---------- input layers ----------

__global__ __launch_bounds__(256) void k_lin0(const float* __restrict__ x, const float* __restrict__ w,
                                              const float* __restrict__ b, float* __restrict__ s){
  int tid = threadIdx.x;
  int g = tid >> 6, o = tid & 63;
  int n = blockIdx.x*4 + g;
  __shared__ float xL[4][F_IN];
  if (tid < 4*F_IN){
    int gg = tid / F_IN, k = tid % F_IN;
    int nn = blockIdx.x*4 + gg;
    xL[gg][k] = (nn < N_NODES) ? x[nn*F_IN + k] : 0.f;
  }
  __syncthreads();
  if (n >= N_NODES) return;
  float acc = b[o];
  #pragma unroll
  for (int k=0;k<F_IN;++k) acc += xL[g][k]*w[k*64+o];
  s[n*64+o] = fmaxf(acc, 0.f);
}

// hid = relu(ea@h1+b1), iteration-invariant; write in SORTED edge order (fp16)
__global__ __launch_bounds__(256) void k_hid(const float* __restrict__ ea,
    const float* __restrict__ h1_w, const float* __restrict__ h1_b,
    const int* __restrict__ pos, _Float16* __restrict__ hidS){
  int tid = threadIdx.x;
  int g = tid >> 7, j = tid & 127;
  __shared__ float eL[2][EAD];
  __shared__ int pL[2];
  if (tid < 8){ int gg = tid>>2, k = tid&3; eL[gg][k] = ea[(blockIdx.x*2+gg)*EAD + k]; }
  if (tid < 2) pL[tid] = pos[blockIdx.x*2 + tid];
  __syncthreads();
  float v = h1_b[j];
  #pragma unroll
  for (int k=0;k<EAD;++k) v += eL[g][k]*h1_w[k*HIDW + j];
  hidS[(size_t)pL[g]*HIDW + j] = (_Float16)fmaxf(v, 0.f);
}

// ---------- fused per-iteration MPNN message kernel ----------
// Block = 16 targets. 8 h-chunks (CH=16). Per chunk: each wave builds P[4 targets]
// in registers -> swizzled 32KB LDS tile -> all waves MFMA vs L2-resident Bpack.
// agg accumulated in MFMA accumulators across chunks. Writes aggsum + Ssum only.
__global__ __launch_bounds__(256) void k_fused_iter(
    const float* __restrict__ s, const _Float16* __restrict__ hidS,
    const int* __restrict__ offs, const int* __restrict__ srcS,
    const _Float16* __restrict__ Bp,
    float* __restrict__ aggsum, float* __restrict__ Ssum)
{
  __shared__ __align__(16) char Pl[16*64*16*2];   // [t][i][h] fp16, swizzled, 32 KB
  int tid = threadIdx.x;
  int w = tid >> 6, lane = tid & 63;
  int t0 = blockIdx.x * 16;
  f32x4 aggacc = {0.f, 0.f, 0.f, 0.f};
  // stage-2 A-frag params
  int tA = lane & 15, kb = lane >> 4;
  int hgA = kb & 1, iofA = kb >> 1;
  unsigned swA_t = (unsigned)(tA & 7) << 4;

  for (int c = 0; c < 8; ++c){
    int c0 = c * 16;
    __syncthreads();   // previous chunk's MFMA reads done
    // ---- P-build: wave w -> targets t0+4w .. t0+4w+3 (independent, no barriers) ----
    for (int q = 0; q < 4; ++q){
      int tl = w*4 + q;
      int tt = t0 + tl;
      int e0 = offs[tt], e1 = offs[tt+1];
      float acc[16];
      #pragma unroll
      for (int h=0; h<16; ++h) acc[h] = 0.f;
      float ss = 0.f;
      for (int ebase = e0; ebase < e1; ebase += 8){
        #pragma unroll
        for (int j = 0; j < 8; ++j){
          int ei = ebase + j;
          if (ei >= e1) break;                       // wave-uniform
          float sv = s[(size_t)srcS[ei]*64 + lane];  // lane = i : direct, no staging
          const f16x8 hv0 = *(const f16x8*)(hidS + (size_t)ei*HIDW + c0);
          const f16x8 hv1 = *(const f16x8*)(hidS + (size_t)ei*HIDW + c0 + 8);
          #pragma unroll
          for (int h=0; h<8; ++h){
            acc[h]   += (float)hv0[h] * sv;
            acc[8+h] += (float)hv1[h] * sv;
          }
          if (c == 0) ss += sv;
        }
      }
      // dump -> P_lds[tl][lane][h], two 16B granules, XOR swizzle (write==read formula)
      unsigned base = (unsigned)tl*2048u + (unsigned)lane*32u;
      unsigned sw = (((unsigned)(tl & 7)) << 4) ^ (((unsigned)(lane & 7)) << 4);
      #pragma unroll
      for (int g2 = 0; g2 < 2; ++g2){
        f16x8 pk;
        #pragma unroll
        for (int h = 0; h < 8; ++h) pk[h] = (_Float16)acc[g2*8 + h];
        *(f16x8*)(Pl + ((base + (unsigned)g2*16u) ^ sw)) = pk;
      }
      if (c == 0) Ssum[(size_t)tt*64 + lane] = ss;
    }
    __syncthreads();   // P chunk ready for all waves
    // ---- stage-2 MFMA: wave w = col-group (16 o-columns) ----
    #pragma unroll 8
    for (int st = 0; st < 32; ++st){
      int iA = st*2 + iofA;
      unsigned abyte = ((unsigned)tA*2048u + (unsigned)iA*32u + (unsigned)hgA*16u)
                       ^ swA_t ^ (((unsigned)(iA & 7)) << 4);
      f16x8 af = *(const f16x8*)(Pl + abyte);
      f16x8 bf = *(const f16x8*)(Bp + ((size_t)((c*32 + st)*4 + w)*64 + lane)*8);
      aggacc = __builtin_amdgcn_mfma_f32_16x16x32_f16(af, bf, aggacc, 0, 0, 0);
    }
  }
  // epilogue: C layout col = lane&15, row = (lane>>4)*4 + r
  int crow0 = (lane >> 4)*4;
  int ccol = w*16 + (lane & 15);
  #pragma unroll
  for (int r = 0; r < 4; ++r)
    aggsum[(size_t)(t0 + crow0 + r)*64 + ccol] = aggacc[r];
}

// fused: mean-deg, bias term (Ssum@h2b), conv-root, relu, GRU cell (in-place on s)
__global__ __launch_bounds__(256) void k_node_update(const float* __restrict__ aggsum,
    const float* __restrict__ Ssum, const float* __restrict__ h2b,
    const float* __restrict__ deg, float* __restrict__ s,
    const float* __restrict__ conv_root, const float* __restrict__ conv_bias,
    const float* __restrict__ WihT, const float* __restrict__ WhhT,
    const float* __restrict__ bih, const float* __restrict__ bhh){
  int tid = threadIdx.x;
  int g = tid >> 6, o = tid & 63;
  int n = blockIdx.x*4 + g;
  __shared__ float hS[4][DD];
  __shared__ float mS[4][DD];
  __shared__ float ssS[4][DD];
  bool valid = n < N_NODES;
  float hold = valid ? s[(size_t)n*DD + o] : 0.f;
  hS[g][o] = hold;
  ssS[g][o] = valid ? Ssum[(size_t)n*DD + o] : 0.f;
  __syncthreads();
  float a = valid ? aggsum[(size_t)n*DD + o] : 0.f;
  #pragma unroll 8
  for (int k=0;k<DD;++k) a += ssS[g][k]*h2b[k*64+o];
  float dinv = valid ? 1.0f/deg[n] : 0.f;
  float acc = a*dinv + conv_bias[o];
  #pragma unroll 8
  for (int k=0;k<DD;++k) acc += hS[g][k]*conv_root[k*64+o];
  float m = fmaxf(acc, 0.f);
  mS[g][o] = m;
  __syncthreads();
  float gi0 = bih[o], gi1 = bih[64+o], gi2 = bih[128+o];
  float gh0 = bhh[o], gh1 = bhh[64+o], gh2 = bhh[128+o];
  for (int k=0;k<DD;++k){
    float mk = mS[g][k], hk = hS[g][k];
    gi0 += mk*WihT[k*192 + o];      gh0 += hk*WhhT[k*192 + o];
    gi1 += mk*WihT[k*192 + 64 + o]; gh1 += hk*WhhT[k*192 + 64 + o];
    gi2 += mk*WihT[k*192 + 128+ o]; gh2 += hk*WhhT[k*192 + 128+ o];
  }
  float r = sigmoidf_(gi0+gh0);
  float z = sigmoidf_(gi1+gh1);
  float nn = tanhf(gi2 + r*gh2);
  float hnew = (1.f - z)*nn + z*hold;
  if (valid) s[(size_t)n*DD + o] = hnew;
}

// ---------- Set2Set (3 steps) + final MLP, fully fused: one block per graph ----------

__global__ __launch_bounds__(256) void k_s2s_all(const float* __restrict__ sND,
    const int* __restrict__ goff,
    const float* __restrict__ IhT, const float* __restrict__ HhT,
    const float* __restrict__ bih, const float* __restrict__ bhh,
    float* __restrict__ ebuf,
    const float* __restrict__ lin1_w, const float* __restrict__ lin1_b,
    const float* __restrict__ lin2_w, const float* __restrict__ lin2_b,
    float* __restrict__ out)
{
  const int CAP = 256;
  __shared__ float sG[256][68];   // padded rows; graph's node slab
  __shared__ float eL[256];
  __shared__ float qL[128], hL[64], cL[64], gate[256];
  __shared__ float red[4], redw[4], red2[4][64];
  int g = blockIdx.x, tid = threadIdx.x;
  int w = tid >> 6, lane = tid & 63;
  int n0 = goff[g], n1 = goff[g+1], cnt = n1 - n0;
  int ncap = cnt < CAP ? cnt : CAP;
  for (int idx = tid; idx < ncap*64; idx += 256)
    sG[idx>>6][idx&63] = sND[(size_t)(n0 + (idx>>6))*64 + (idx&63)];
  if (tid < 128) qL[tid] = 0.f;
  if (tid < 64){ hL[tid] = 0.f; cL[tid] = 0.f; }
  __syncthreads();
  for (int step = 0; step < 3; ++step){
    // LSTM gates (one gate per thread)
    float acc = bih[tid] + bhh[tid];
    #pragma unroll 8
    for (int k=0;k<128;++k) acc += qL[k]*IhT[k*256 + tid];
    #pragma unroll 8
    for (int k=0;k<64;++k)  acc += hL[k]*HhT[k*256 + tid];
    gate[tid] = acc;
    __syncthreads();
    if (tid < 64){
      float i = sigmoidf_(gate[tid]);
      float f = sigmoidf_(gate[64+tid]);
      float gg = tanhf(gate[128+tid]);
      float o = sigmoidf_(gate[192+tid]);
      float cc = f*cL[tid] + i*gg;
      hL[tid] = o*tanhf(cc);
      cL[tid] = cc;
    }
    __syncthreads();
    // pass 1: e_n + per-graph max (wave per row, LDS slab)
    float wmax = -INFINITY;
    for (int r = w; r < cnt; r += 4){
      float v = (r < CAP) ? sG[r][lane] : sND[(size_t)(n0+r)*64 + lane];
      float p = v * hL[lane];
      #pragma unroll
      for (int s2=32; s2>0; s2>>=1) p += __shfl_xor(p, s2, 64);
      if (lane == 0){ if (r < CAP) eL[r] = p; else ebuf[n0+r] = p; }
      wmax = fmaxf(wmax, p);
    }
    if (lane == 0) red[w] = wmax;
    __syncthreads();
    float m = fmaxf(fmaxf(red[0], red[1]), fmaxf(red[2], red[3]));
    // pass 2: a = exp(e-m); weighted sum + normalizer
    float racc = 0.f, ws = 0.f;
    for (int r = w; r < cnt; r += 4){
      float e = (r < CAP) ? eL[r] : ebuf[n0+r];
      float a = expf(e - m);
      float v = (r < CAP) ? sG[r][lane] : sND[(size_t)(n0+r)*64 + lane];
      racc += a * v;
      ws += a;
    }
    red2[w][lane] = racc;
    if (lane == 0) redw[w] = ws;
    __syncthreads();
    if (tid < 64){
      float rs = red2[0][lane]+red2[1][lane]+red2[2][lane]+red2[3][lane];
      float st = redw[0]+redw[1]+redw[2]+redw[3];
      float rr = (st > 0.f) ? rs/st : 0.f;
      qL[lane] = hL[lane];
      qL[64+lane] = rr;
    }
    __syncthreads();
  }
  // final MLP: y = relu(qstar@lin1+b1)@lin2+b2
  {
    float facc = 0.f;
    for (int k = w*32; k < w*32+32; ++k) facc += qL[k]*lin1_w[k*64 + lane];
    red2[w][lane] = facc;
  }
  __syncthreads();
  if (tid < 64){
    float z = fmaxf(lin1_b[lane] + red2[0][lane]+red2[1][lane]+red2[2][lane]+red2[3][lane], 0.f);
    float p = z * lin2_w[lane];
    #pragma unroll
    for (int s2=32; s2>0; s2>>=1) p += __shfl_xor(p, s2, 64);
    if (lane == 0) out[g] = p + lin2_b[0];
  }
}

// ---------- launch ----------

static inline size_t alignup(size_t x){ return (x + 255) & ~(size_t)255; }

extern "C" void kernel_launch(void* const* d_in, const int* in_sizes, int n_in,
                              void* d_out, int out_size, void* d_ws, size_t ws_size,
                              hipStream_t stream){
  const float* x      = (const float*)d_in[0];
  const int*   ei     = (const int*)  d_in[1];
  const float* ea     = (const float*)d_in[2];
  const int*   batch  = (const int*)  d_in[3];
  const float* lin0_w = (const float*)d_in[5];
  const float* lin0_b = (const float*)d_in[6];
  const float* h1_w   = (const float*)d_in[7];
  const float* h1_b   = (const float*)d_in[8];
  const float* h2_w   = (const float*)d_in[9];
  const float* h2_b   = (const float*)d_in[10];
  const float* conv_root = (const float*)d_in[11];
  const float* conv_bias = (const float*)d_in[12];
  const float* gru_w_ih  = (const float*)d_in[13];
  const float* gru_w_hh  = (const float*)d_in[14];
  const float* gru_b_ih  = (const float*)d_in[15];
  const float* gru_b_hh  = (const float*)d_in[16];
  const float* lstm_w_ih = (const float*)d_in[17];
  const float* lstm_w_hh = (const float*)d_in[18];
  const float* lstm_b_ih = (const float*)d_in[19];
  const float* lstm_b_hh = (const float*)d_in[20];
  const float* lin1_w = (const float*)d_in[21];
  const float* lin1_b = (const float*)d_in[22];
  const float* lin2_w = (const float*)d_in[23];
  const float* lin2_b = (const float*)d_in[24];
  (void)in_sizes; (void)n_in; (void)out_size; (void)ws_size;

  const int* srcA = ei;
  const int* tgtA = ei + N_EDGES;

  // ---- workspace layout (~32 MB) ----
  char* p = (char*)d_ws;
  size_t off = 0;
  auto take = [&](size_t bytes)->char*{ char* q = p + off; off = alignup(off + bytes); return q; };
  _Float16* Bpack = (_Float16*)take((size_t)8*32*4*64*8*2);        // 1.05 MB
  float* sbuf     = (float*)take((size_t)N_NODES*DD*4);
  float* aggsum   = (float*)take((size_t)N_NODES*DD*4);
  float* Ssum     = (float*)take((size_t)N_NODES*DD*4);
  _Float16* hidS  = (_Float16*)take((size_t)N_EDGES*HIDW*2);       // 20.48 MB
  float* WihT    = (float*)take(12288*4);
  float* WhhT    = (float*)take(12288*4);
  float* IhT     = (float*)take(32768*4);
  float* HhT     = (float*)take(16384*4);
  float* deg     = (float*)take(N_NODES*4);
  int*   cnt     = (int*)  take(N_NODES*4);
  int*   offs    = (int*)  take((N_NODES+1)*4);
  int*   cursor  = (int*)  take(N_NODES*4);
  int*   srcS    = (int*)  take(N_EDGES*4);
  int*   pos     = (int*)  take(N_EDGES*4);
  int*   goff    = (int*)  take(65*4);
  float* ebuf    = (float*)take(N_NODES*4);

  hipMemsetAsync(cnt, 0, N_NODES*4, stream);

  k_prep_bpack<<<(8*32*4*64*8)/256, 256, 0, stream>>>(h2_w, Bpack);
  k_prep_wT<<<(12288*2+32768+16384)/256, 256, 0, stream>>>(gru_w_ih, gru_w_hh, lstm_w_ih, lstm_w_hh,
                                                           WihT, WhhT, IhT, HhT);
  k_count<<<(N_EDGES+255)/256, 256, 0, stream>>>(tgtA, cnt);
  k_scan<<<1, 1024, 0, stream>>>(cnt, offs, cursor, deg);
  k_sortE<<<(N_EDGES+255)/256, 256, 0, stream>>>(tgtA, srcA, cursor, srcS, pos);
  k_graphoff<<<1, 128, 0, stream>>>(batch, goff);
  k_lin0<<<N_NODES/4, 256, 0, stream>>>(x, lin0_w, lin0_b, sbuf);
  k_hid<<<N_EDGES/2, 256, 0, stream>>>(ea, h1_w, h1_b, pos, hidS);

  for (int it = 0; it < 3; ++it){
    k_fused_iter<<<N_NODES/16, 256, 0, stream>>>(sbuf, hidS, offs, srcS, Bpack, aggsum, Ssum);
    k_node_update<<<N_NODES/4, 256, 0, stream>>>(aggsum, Ssum, h2_b, deg, sbuf, conv_root, conv_bias,
                                                 WihT, WhhT, gru_b_ih, gru_b_hh);
  }

  k_s2s_all<<<N_GRAPH, 256, 0, stream>>>(sbuf, goff, IhT, HhT, lstm_b_ih, lstm_b_hh, ebuf,
                                         lin1_w, lin1_b, lin2_w, lin2_b, (float*)d_out);
}

// Round 10
// 665.985 us; speedup vs baseline: 1.4413x; 1.4413x over previous
//
#include <hip/hip_runtime.h>
#include <math.h>

#define N_NODES 10000
#define N_EDGES 80000
#define N_GRAPH 64
#define DD 64
#define HIDW 128
#define F_IN 14
#define EAD 4

typedef _Float16 f16x8 __attribute__((ext_vector_type(8)));
typedef float f32x4 __attribute__((ext_vector_type(4)));

__device__ __forceinline__ float sigmoidf_(float x){ return 1.0f/(1.0f+expf(-x)); }

// ---------- fused prep: Bpack + weight transposes + count + graphoff + lin0 ----------
// Bp[((st*4+cg)*64+lane)*8+j] = h2w[h*4096+i*64+o], k=st*32+(lane>>4)*8+j (st 0..255),
// h=k>>6, i=k&63, o=cg*16+(lane&15)   [K-order = h*64+i, matches P layout [t][h][i]]
__global__ __launch_bounds__(256) void k_prep_misc(
    const float* __restrict__ h2w, _Float16* __restrict__ Bp,
    const float* __restrict__ gih, const float* __restrict__ ghh,
    const float* __restrict__ lih, const float* __restrict__ lhh,
    float* __restrict__ WihT, float* __restrict__ WhhT,
    float* __restrict__ IhT,  float* __restrict__ HhT,
    const int* __restrict__ tgt, int* __restrict__ cnt,
    const int* __restrict__ batch, int* __restrict__ goff,
    const float* __restrict__ x, const float* __restrict__ l0w,
    const float* __restrict__ l0b, float* __restrict__ s)
{
  int idx = blockIdx.x*256 + threadIdx.x;
  if (idx < 524288){
    int j = idx & 7, l = (idx >> 3) & 63, cg = (idx >> 9) & 3, st = idx >> 11;
    int k = st*32 + ((l >> 4) << 3) + j;
    int h = k >> 6, i = k & 63, o = cg*16 + (l & 15);
    Bp[idx] = (_Float16)h2w[(size_t)h*4096 + i*64 + o];
    return;
  }
  idx -= 524288;
  if (idx < 12288){ int k=idx/192, j=idx%192; WihT[idx]=gih[j*64+k]; return; }
  idx -= 12288;
  if (idx < 12288){ int k=idx/192, j=idx%192; WhhT[idx]=ghh[j*64+k]; return; }
  idx -= 12288;
  if (idx < 32768){ int k=idx>>8, j=idx&255; IhT[idx]=lih[j*128+k]; return; }
  idx -= 32768;
  if (idx < 16384){ int k=idx>>8, j=idx&255; HhT[idx]=lhh[j*64+k]; return; }
  idx -= 16384;
  if (idx < N_EDGES){ atomicAdd(&cnt[tgt[idx]], 1); return; }
  idx -= N_EDGES;
  if (idx < 65){
    int g = idx, lo = 0, hi = N_NODES;
    while (lo < hi){ int mid = (lo+hi)>>1; if (batch[mid] < g) lo = mid+1; else hi = mid; }
    goff[g] = lo; return;
  }
  idx -= 65;
  if (idx < N_NODES*64){
    int n = idx >> 6, o = idx & 63;
    float acc = l0b[o];
    #pragma unroll
    for (int k=0;k<F_IN;++k) acc += x[n*F_IN + k]*l0w[k*64 + o];
    s[idx] = fmaxf(acc, 0.f);
    return;
  }
}
#define PREP_TOT (524288 + 12288 + 12288 + 32768 + 16384 + N_EDGES + 65 + N_NODES*64)

// ---------- CSR build ----------

__global__ __launch_bounds__(1024) void k_scan(const int* __restrict__ cnt, int* __restrict__ offs,
                                               int* __restrict__ cursor, float* __restrict__ deg){
  __shared__ int sc[1024];
  int t = threadIdx.x;
  int base = t*10;
  int loc[10]; int tot = 0;
  #pragma unroll
  for (int j=0;j<10;++j){
    int i = base+j;
    int c = (i < N_NODES) ? cnt[i] : 0;
    loc[j] = tot; tot += c;
  }
  sc[t] = tot; __syncthreads();
  for (int st=1; st<1024; st<<=1){
    int v = (t>=st) ? sc[t-st] : 0;
    __syncthreads();
    sc[t] += v;
    __syncthreads();
  }
  int ex = sc[t] - tot;
  #pragma unroll
  for (int j=0;j<10;++j){
    int i = base+j;
    if (i < N_NODES){
      int o = ex + loc[j];
      offs[i] = o; cursor[i] = o;
      int c = cnt[i];
      deg[i] = (float)(c > 0 ? c : 1);
    }
  }
  if (t == 1023) offs[N_NODES] = sc[1023];
}

__global__ void k_sortE(const int* __restrict__ tgt, const int* __restrict__ src,
                        int* __restrict__ cursor, int* __restrict__ srcS, int* __restrict__ pos){
  int e = blockIdx.x*256 + threadIdx.x;
  if (e < N_EDGES){
    int p = atomicAdd(&cursor[tgt[e]], 1);
    srcS[p] = src[e];
    pos[e] = p;
  }
}

// hid = relu(ea@h1+b1), iteration-invariant; write in SORTED edge order (fp16)
__global__ __launch_bounds__(256) void k_hid(const float* __restrict__ ea,
    const float* __restrict__ h1_w, const float* __restrict__ h1_b,
    const int* __restrict__ pos, _Float16* __restrict__ hidS){
  int tid = threadIdx.x;
  int g = tid >> 7, j = tid & 127;
  __shared__ float eL[2][EAD];
  __shared__ int pL[2];
  if (tid < 8){ int gg = tid>>2, k = tid&3; eL[gg][k] = ea[(blockIdx.x*2+gg)*EAD + k]; }
  if (tid < 2) pL[tid] = pos[blockIdx.x*2 + tid];
  __syncthreads();
  float v = h1_b[j];
  #pragma unroll
  for (int k=0;k<EAD;++k) v += eL[g][k]*h1_w[k*HIDW + j];
  hidS[(size_t)pL[g]*HIDW + j] = (_Float16)fmaxf(v, 0.f);
}

// ---------- stage 1: P build (fp16, [t][h][i] layout, vectorized 16B stores) ----------
// thread: i8 = tid&7 (i = i8*8+ii), hb = tid>>3 (h = hb*4+r). acc[4][8].
// hid LDS tile stored TRANSPOSED: hidT[j][(h&3)*32 + (h>>2)] so reads hidT[j][r*32+hb]
// are conflict-free (8 distinct consecutive banks per wave, broadcast over i8).
__global__ __launch_bounds__(256) void k_aggpre(
    const float* __restrict__ s, const _Float16* __restrict__ hidS,
    const int* __restrict__ offs, const int* __restrict__ srcS,
    _Float16* __restrict__ P, float* __restrict__ Ssum){
  int t = blockIdx.x;
  int tid = threadIdx.x;
  int i8 = tid & 7, hb = tid >> 3;
  __shared__ float sL[8][64];
  __shared__ float hidT[8][128];
  float acc[4][8];
  #pragma unroll
  for (int r=0;r<4;++r)
    #pragma unroll
    for (int ii=0;ii<8;++ii) acc[r][ii] = 0.f;
  float ss[8];
  #pragma unroll
  for (int ii=0;ii<8;++ii) ss[ii] = 0.f;
  int e0 = offs[t], e1 = offs[t+1];
  for (int base = e0; base < e1; base += 8){
    int ecnt = min(8, e1 - base);
    __syncthreads();
    for (int a = tid; a < ecnt*64; a += 256){
      int j = a >> 6, ii = a & 63;
      sL[j][ii] = s[(size_t)srcS[base+j]*64 + ii];
    }
    for (int a = tid; a < ecnt*128; a += 256){
      int j = a >> 7, hh = a & 127;
      hidT[j][(hh & 3)*32 + (hh >> 2)] = (float)hidS[(size_t)(base+j)*HIDW + hh];
    }
    __syncthreads();
    for (int j=0;j<ecnt;++j){
      float hv[4], sv[8];
      #pragma unroll
      for (int r=0;r<4;++r) hv[r] = hidT[j][r*32 + hb];
      #pragma unroll
      for (int ii=0;ii<8;++ii) sv[ii] = sL[j][i8*8 + ii];
      #pragma unroll
      for (int r=0;r<4;++r)
        #pragma unroll
        for (int ii=0;ii<8;++ii) acc[r][ii] += hv[r]*sv[ii];
      if (hb == 0){
        #pragma unroll
        for (int ii=0;ii<8;++ii) ss[ii] += sv[ii];
      }
    }
  }
  _Float16* row = P + (size_t)t*8192;
  #pragma unroll
  for (int r=0;r<4;++r){
    f16x8 pk;
    #pragma unroll
    for (int ii=0;ii<8;++ii) pk[ii] = (_Float16)acc[r][ii];
    *(f16x8*)(row + (hb*4 + r)*64 + i8*8) = pk;
  }
  if (hb == 0){
    float4 v0 = make_float4(ss[0],ss[1],ss[2],ss[3]);
    float4 v1 = make_float4(ss[4],ss[5],ss[6],ss[7]);
    *(float4*)(Ssum + (size_t)t*64 + i8*8)     = v0;
    *(float4*)(Ssum + (size_t)t*64 + i8*8 + 4) = v1;
  }
}

// ---------- stage 2 + node update fused ----------
// Block = 16 rows. Full K=8192 in-kernel (8 slots of 1024 halves, double-buffered LDS).
// Epilogue: Ssum@h2b + /deg + conv_root + relu + GRU, writes s in place.
__global__ __launch_bounds__(256) void k_gemm_fused(
    const _Float16* __restrict__ A, const _Float16* __restrict__ Bp,
    const float* __restrict__ Ssum, const float* __restrict__ h2b,
    const float* __restrict__ deg, float* __restrict__ s,
    const float* __restrict__ conv_root, const float* __restrict__ conv_bias,
    const float* __restrict__ WihT, const float* __restrict__ WhhT,
    const float* __restrict__ bih, const float* __restrict__ bhh)
{
  __shared__ _Float16 tile[2][16*1024];
  __shared__ float aggL[16][68];
  __shared__ float hS[16][64];
  __shared__ float xS[16][68];    // ssS, later reused as mS
  int tid = threadIdx.x;
  int t0 = blockIdx.x*16;
  const size_t rowB = (size_t)8192*2;
  int sub = tid >> 7, colb = (tid & 127)*16;
  const char* Ab = (const char*)A + (size_t)t0*rowB;
  f16x8 rg[8];
  int cg = tid >> 6, lane = tid & 63;
  int row = lane & 15, kb = lane >> 4;
  int swz = (row & 7) << 4;
  f32x4 acc = {0.f,0.f,0.f,0.f};

  // prologue: stage slot 0
  #pragma unroll
  for (int i2=0;i2<8;++i2){
    int r = i2*2 + sub;
    rg[i2] = *(const f16x8*)(Ab + (size_t)r*rowB + (size_t)(colb ^ ((r&7)<<4)));
  }
  #pragma unroll
  for (int i2=0;i2<8;++i2){
    int r = i2*2 + sub;
    *(f16x8*)((char*)tile[0] + r*2048 + colb) = rg[i2];
  }
  for (int y = 0; y < 8; ++y){
    if (y < 7){
      #pragma unroll
      for (int i2=0;i2<8;++i2){
        int r = i2*2 + sub;
        rg[i2] = *(const f16x8*)(Ab + (size_t)r*rowB + (size_t)(y+1)*2048 + (size_t)(colb ^ ((r&7)<<4)));
      }
    }
    __syncthreads();     // tile[y&1] fully written
    const char* tb = (const char*)tile[y&1] + row*2048;
    int fr0 = y*128;
    #pragma unroll 8
    for (int st = 0; st < 32; ++st){
      f16x8 af = *(const f16x8*)(tb + ((st*64 + kb*16) ^ swz));
      f16x8 bf = *(const f16x8*)(Bp + ((size_t)(fr0 + st*4 + cg)*64 + lane)*8);
      acc = __builtin_amdgcn_mfma_f32_16x16x32_f16(af, bf, acc, 0, 0, 0);
    }
    if (y < 7){
      #pragma unroll
      for (int i2=0;i2<8;++i2){
        int r = i2*2 + sub;
        *(f16x8*)((char*)tile[(y+1)&1] + r*2048 + colb) = rg[i2];
      }
    }
  }
  // epilogue: agg -> LDS; stage h(=s), ssS
  #pragma unroll
  for (int r=0;r<4;++r) aggL[kb*4 + r][cg*16 + row] = acc[r];
  for (int a = tid; a < 1024; a += 256){
    int nn = a >> 6, o = a & 63;
    hS[nn][o] = s[(size_t)(t0+nn)*64 + o];
    xS[nn][o] = Ssum[(size_t)(t0+nn)*64 + o];
  }
  __syncthreads();
  int o = tid & 63, ng = tid >> 6;   // nodes ng, ng+4, ng+8, ng+12
  float aM[4];
  #pragma unroll
  for (int u=0;u<4;++u) aM[u] = aggL[ng + 4*u][o];
  for (int k=0;k<64;++k){
    float w2 = h2b[k*64 + o];
    #pragma unroll
    for (int u=0;u<4;++u) aM[u] += xS[ng + 4*u][k]*w2;
  }
  #pragma unroll
  for (int u=0;u<4;++u) aM[u] = aM[u]/deg[t0 + ng + 4*u] + conv_bias[o];
  for (int k=0;k<64;++k){
    float cr = conv_root[k*64 + o];
    #pragma unroll
    for (int u=0;u<4;++u) aM[u] += hS[ng + 4*u][k]*cr;
  }
  float mM[4];
  #pragma unroll
  for (int u=0;u<4;++u) mM[u] = fmaxf(aM[u], 0.f);
  __syncthreads();                 // all xS (ssS) reads done
  #pragma unroll
  for (int u=0;u<4;++u) xS[ng + 4*u][o] = mM[u];   // xS now holds m
  __syncthreads();
  float gi0[4], gi1[4], gi2[4], gh0[4], gh1[4], gh2[4];
  #pragma unroll
  for (int u=0;u<4;++u){
    gi0[u] = bih[o];     gh0[u] = bhh[o];
    gi1[u] = bih[64+o];  gh1[u] = bhh[64+o];
    gi2[u] = bih[128+o]; gh2[u] = bhh[128+o];
  }
  for (int k=0;k<64;++k){
    float wi0 = WihT[k*192 + o], wi1 = WihT[k*192 + 64 + o], wi2 = WihT[k*192 + 128 + o];
    float wh0 = WhhT[k*192 + o], wh1 = WhhT[k*192 + 64 + o], wh2 = WhhT[k*192 + 128 + o];
    #pragma unroll
    for (int u=0;u<4;++u){
      float mk = xS[ng + 4*u][k], hk = hS[ng + 4*u][k];
      gi0[u] += mk*wi0; gh0[u] += hk*wh0;
      gi1[u] += mk*wi1; gh1[u] += hk*wh1;
      gi2[u] += mk*wi2; gh2[u] += hk*wh2;
    }
  }
  #pragma unroll
  for (int u=0;u<4;++u){
    int nn = ng + 4*u;
    float r = sigmoidf_(gi0[u] + gh0[u]);
    float z = sigmoidf_(gi1[u] + gh1[u]);
    float nv = tanhf(gi2[u] + r*gh2[u]);
    float hnew = (1.f - z)*nv + z*hS[nn][o];
    s[(size_t)(t0+nn)*64 + o] = hnew;
  }
}

// ---------- Set2Set (3 steps) + final MLP, fully fused: one block per graph ----------

__global__ __launch_bounds__(256) void k_s2s_all(const float* __restrict__ sND,
    const int* __restrict__ goff,
    const float* __restrict__ IhT, const float* __restrict__ HhT,
    const float* __restrict__ bih, const float* __restrict__ bhh,
    float* __restrict__ ebuf,
    const float* __restrict__ lin1_w, const float* __restrict__ lin1_b,
    const float* __restrict__ lin2_w, const float* __restrict__ lin2_b,
    float* __restrict__ out)
{
  const int CAP = 256;
  __shared__ float sG[256][68];
  __shared__ float eL[256];
  __shared__ float qL[128], hL[64], cL[64], gate[256];
  __shared__ float red[4], redw[4], red2[4][64];
  int g = blockIdx.x, tid = threadIdx.x;
  int w = tid >> 6, lane = tid & 63;
  int n0 = goff[g], n1 = goff[g+1], cnt = n1 - n0;
  int ncap = cnt < CAP ? cnt : CAP;
  for (int idx = tid; idx < ncap*64; idx += 256)
    sG[idx>>6][idx&63] = sND[(size_t)(n0 + (idx>>6))*64 + (idx&63)];
  if (tid < 128) qL[tid] = 0.f;
  if (tid < 64){ hL[tid] = 0.f; cL[tid] = 0.f; }
  __syncthreads();
  for (int step = 0; step < 3; ++step){
    float acc = bih[tid] + bhh[tid];
    #pragma unroll 8
    for (int k=0;k<128;++k) acc += qL[k]*IhT[k*256 + tid];
    #pragma unroll 8
    for (int k=0;k<64;++k)  acc += hL[k]*HhT[k*256 + tid];
    gate[tid] = acc;
    __syncthreads();
    if (tid < 64){
      float i = sigmoidf_(gate[tid]);
      float f = sigmoidf_(gate[64+tid]);
      float gg = tanhf(gate[128+tid]);
      float o = sigmoidf_(gate[192+tid]);
      float cc = f*cL[tid] + i*gg;
      hL[tid] = o*tanhf(cc);
      cL[tid] = cc;
    }
    __syncthreads();
    float wmax = -INFINITY;
    for (int r = w; r < cnt; r += 4){
      float v = (r < CAP) ? sG[r][lane] : sND[(size_t)(n0+r)*64 + lane];
      float p = v * hL[lane];
      #pragma unroll
      for (int s2=32; s2>0; s2>>=1) p += __shfl_xor(p, s2, 64);
      if (lane == 0){ if (r < CAP) eL[r] = p; else ebuf[n0+r] = p; }
      wmax = fmaxf(wmax, p);
    }
    if (lane == 0) red[w] = wmax;
    __syncthreads();
    float m = fmaxf(fmaxf(red[0], red[1]), fmaxf(red[2], red[3]));
    float racc = 0.f, ws = 0.f;
    for (int r = w; r < cnt; r += 4){
      float e = (r < CAP) ? eL[r] : ebuf[n0+r];
      float a = expf(e - m);
      float v = (r < CAP) ? sG[r][lane] : sND[(size_t)(n0+r)*64 + lane];
      racc += a * v;
      ws += a;
    }
    red2[w][lane] = racc;
    if (lane == 0) redw[w] = ws;
    __syncthreads();
    if (tid < 64){
      float rs = red2[0][lane]+red2[1][lane]+red2[2][lane]+red2[3][lane];
      float st = redw[0]+redw[1]+redw[2]+redw[3];
      float rr = (st > 0.f) ? rs/st : 0.f;
      qL[lane] = hL[lane];
      qL[64+lane] = rr;
    }
    __syncthreads();
  }
  {
    float facc = 0.f;
    for (int k = w*32; k < w*32+32; ++k) facc += qL[k]*lin1_w[k*64 + lane];
    red2[w][lane] = facc;
  }
  __syncthreads();
  if (tid < 64){
    float z = fmaxf(lin1_b[lane] + red2[0][lane]+red2[1][lane]+red2[2][lane]+red2[3][lane], 0.f);
    float p = z * lin2_w[lane];
    #pragma unroll
    for (int s2=32; s2>0; s2>>=1) p += __shfl_xor(p, s2, 64);
    if (lane == 0) out[g] = p + lin2_b[0];
  }
}

// ---------- launch ----------

static inline size_t alignup(size_t x){ return (x + 255) & ~(size_t)255; }

extern "C" void kernel_launch(void* const* d_in, const int* in_sizes, int n_in,
                              void* d_out, int out_size, void* d_ws, size_t ws_size,
                              hipStream_t stream){
  const float* x      = (const float*)d_in[0];
  const int*   ei     = (const int*)  d_in[1];
  const float* ea     = (const float*)d_in[2];
  const int*   batch  = (const int*)  d_in[3];
  const float* lin0_w = (const float*)d_in[5];
  const float* lin0_b = (const float*)d_in[6];
  const float* h1_w   = (const float*)d_in[7];
  const float* h1_b   = (const float*)d_in[8];
  const float* h2_w   = (const float*)d_in[9];
  const float* h2_b   = (const float*)d_in[10];
  const float* conv_root = (const float*)d_in[11];
  const float* conv_bias = (const float*)d_in[12];
  const float* gru_w_ih  = (const float*)d_in[13];
  const float* gru_w_hh  = (const float*)d_in[14];
  const float* gru_b_ih  = (const float*)d_in[15];
  const float* gru_b_hh  = (const float*)d_in[16];
  const float* lstm_w_ih = (const float*)d_in[17];
  const float* lstm_w_hh = (const float*)d_in[18];
  const float* lstm_b_ih = (const float*)d_in[19];
  const float* lstm_b_hh = (const float*)d_in[20];
  const float* lin1_w = (const float*)d_in[21];
  const float* lin1_b = (const float*)d_in[22];
  const float* lin2_w = (const float*)d_in[23];
  const float* lin2_b = (const float*)d_in[24];
  (void)in_sizes; (void)n_in; (void)out_size; (void)ws_size;

  const int* srcA = ei;
  const int* tgtA = ei + N_EDGES;

  // ---- workspace layout (~192 MB) ----
  char* p = (char*)d_ws;
  size_t off = 0;
  auto take = [&](size_t bytes)->char*{ char* q = p + off; off = alignup(off + bytes); return q; };
  _Float16* Bpack = (_Float16*)take((size_t)524288*2);             // 1.05 MB
  float* sbuf     = (float*)take((size_t)N_NODES*DD*4);
  float* Ssum     = (float*)take((size_t)N_NODES*DD*4);
  _Float16* hidS  = (_Float16*)take((size_t)N_EDGES*HIDW*2);       // 20.48 MB
  float* WihT    = (float*)take(12288*4);
  float* WhhT    = (float*)take(12288*4);
  float* IhT     = (float*)take(32768*4);
  float* HhT     = (float*)take(16384*4);
  float* deg     = (float*)take(N_NODES*4);
  int*   cnt     = (int*)  take(N_NODES*4);
  int*   offs    = (int*)  take((N_NODES+1)*4);
  int*   cursor  = (int*)  take(N_NODES*4);
  int*   srcS    = (int*)  take(N_EDGES*4);
  int*   pos     = (int*)  take(N_EDGES*4);
  int*   goff    = (int*)  take(65*4);
  float* ebuf    = (float*)take(N_NODES*4);
  _Float16* Pbuf = (_Float16*)take((size_t)N_NODES*8192*2);        // 163.84 MB

  hipMemsetAsync(cnt, 0, N_NODES*4, stream);

  k_prep_misc<<<(PREP_TOT + 255)/256, 256, 0, stream>>>(
      h2_w, Bpack, gru_w_ih, gru_w_hh, lstm_w_ih, lstm_w_hh,
      WihT, WhhT, IhT, HhT, tgtA, cnt, batch, goff, x, lin0_w, lin0_b, sbuf);
  k_scan<<<1, 1024, 0, stream>>>(cnt, offs, cursor, deg);
  k_sortE<<<(N_EDGES+255)/256, 256, 0, stream>>>(tgtA, srcA, cursor, srcS, pos);
  k_hid<<<N_EDGES/2, 256, 0, stream>>>(ea, h1_w, h1_b, pos, hidS);

  for (int it = 0; it < 3; ++it){
    k_aggpre<<<N_NODES, 256, 0, stream>>>(sbuf, hidS, offs, srcS, Pbuf, Ssum);
    k_gemm_fused<<<N_NODES/16, 256, 0, stream>>>(Pbuf, Bpack, Ssum, h2_b, deg, sbuf,
                                                 conv_root, conv_bias, WihT, WhhT,
                                                 gru_b_ih, gru_b_hh);
  }

  k_s2s_all<<<N_GRAPH, 256, 0, stream>>>(sbuf, goff, IhT, HhT, lstm_b_ih, lstm_b_hh, ebuf,
                                         lin1_w, lin1_b, lin2_w, lin2_b, (float*)d_out);
}